// Round 9
// baseline (130.986 us; speedup 1.0000x reference)
//
#include <hip/hip_runtime.h>

#define N2 16384
#define N1 65536

// ---- output layout (float offsets) ----
#define OUT_AIM 7225344         // 21*21*N2
#define OUT_LD  14450688        // 2*21*21*N2
#define OUT_ZRE 14450689
#define OUT_ZIM 14794753        // OUT_ZRE + 21*N2

// ---- LDS layout (float offsets), TILE_J = 64 ----
#define T2STR  72
#define L_T2R  0                // [20][72]
#define L_T2I  1440             // [20][72]
#define L_M2   2880             // [c:2][u:4][64]
#define L_SC   3392             // [idx:26][u:4][64]
#define L_IS2R 10048            // [64]
#define L_IS2I 10112            // [64]
#define L_RED  10176            // [14]
#define L_TOT  10190            // ~40.8 KB

#define SC(idx, u, jl) lds[L_SC + (((idx)*4 + (u)) * 64) + (jl)]
#define SCOFF(idx, u)  (L_SC + (((idx)*4 + (u)) * 64))
#define LDSF4(off)     (*reinterpret_cast<const float4*>(&lds[(off)]))

// 16-byte packed store of 4 adjacent floats (global_store_dwordx4)
#define ST4(addr, a0, a1, a2, a3) do {                                        \
    float4 _o; _o.x=(a0); _o.y=(a1); _o.z=(a2); _o.w=(a3);                    \
    *reinterpret_cast<float4*>(addr) = _o; } while (0)

// ---- workspace: 256 doubles (per-block logdet partials), reduced by the
// tiny finalize dispatch (stream-ordered; kernel-boundary release/acquire).

// ---- phase-2 per-row-slot machinery (2 rows max per wave) ----
#define SLOT_PREP(s, P)                                                       \
    const int  p##s = (P);                                                    \
    const bool is20_##s = (p##s == 20);                                       \
    const int  ap_##s = p##s >> 2, up_##s = p##s & 3;                         \
    const bool sc_##s = (!is20_##s) && (h == up_##s);                         \
    float ppr_##s[4], ppi_##s[4], par_##s[4], pai_##s[4];                     \
    float zar_##s[4] = {0.f,0.f,0.f,0.f}, zai_##s[4] = {0.f,0.f,0.f,0.f};     \
    _Pragma("unroll") for (int j = 0; j < 4; ++j) {                           \
        ppr_##s[j]=0.f; ppi_##s[j]=0.f; par_##s[j]=0.f; pai_##s[j]=0.f; }     \
    if (!is20_##s) {                                                          \
        const float4 tr4 = LDSF4(L_T2R + p##s*T2STR + c4);                    \
        const float4 ti4 = LDSF4(L_T2I + p##s*T2STR + c4);                    \
        const float tpr[4] = {tr4.x, tr4.y, tr4.z, tr4.w};                    \
        const float tpi[4] = {ti4.x, ti4.y, ti4.z, ti4.w};                    \
        _Pragma("unroll") for (int j = 0; j < 4; ++j) {                       \
            ppr_##s[j] = tpr[j]*is2r[j] - tpi[j]*is2i[j];                     \
            ppi_##s[j] = tpr[j]*is2i[j] + tpi[j]*is2r[j]; }                   \
        if (ap_##s < 4) {                                                     \
            const float4 pr4 = LDSF4(SCOFF(8+ap_##s,  up_##s) + c4);          \
            const float4 pi4 = LDSF4(SCOFF(12+ap_##s, up_##s) + c4);          \
            par_##s[0]=pr4.x; par_##s[1]=pr4.y; par_##s[2]=pr4.z; par_##s[3]=pr4.w; \
            pai_##s[0]=pi4.x; pai_##s[1]=pi4.y; pai_##s[2]=pi4.z; pai_##s[3]=pi4.w; \
        }                                                                     \
    }

// main q rows: q = 4*qi + h < 20 (qi = 0..4). Scatter b = qi when h == up.
#define SLOT_QMAIN(s) do {                                                    \
    float ar[4], ai[4];                                                       \
    if (is20_##s) {                                                           \
        _Pragma("unroll") for (int j = 0; j < 4; ++j) {                       \
            ar[j] = -(tq[j]*is2r[j] - uq[j]*is2i[j]);                         \
            ai[j] =   tq[j]*is2i[j] + uq[j]*is2r[j]; }                        \
    } else {                                                                  \
        _Pragma("unroll") for (int j = 0; j < 4; ++j) {                       \
            ar[j] = ppr_##s[j]*tq[j] + ppi_##s[j]*uq[j];                      \
            ai[j] = ppi_##s[j]*tq[j] - ppr_##s[j]*uq[j]; }                    \
        if (sc_##s) {                                                         \
            if (ap_##s < 4) {                                                 \
                if (qi < 4) {                                                 \
                    const float4 br4 = LDSF4(SCOFF(qi,   up_##s) + c4);       \
                    const float4 bi4 = LDSF4(SCOFF(4+qi, up_##s) + c4);       \
                    const float tb[4] = {br4.x, br4.y, br4.z, br4.w};         \
                    const float ub[4] = {bi4.x, bi4.y, bi4.z, bi4.w};         \
                    _Pragma("unroll") for (int j = 0; j < 4; ++j) {           \
                        ar[j] += par_##s[j]*tb[j] + pai_##s[j]*ub[j];         \
                        ai[j] += pai_##s[j]*tb[j] - par_##s[j]*ub[j]; }       \
                    if (qi == ap_##s) {        /* + 1/lam00 */                \
                        const float4 ir4 = LDSF4(SCOFF(16+ap_##s, up_##s) + c4); \
                        const float4 ii4 = LDSF4(SCOFF(20+ap_##s, up_##s) + c4); \
                        ar[0]+=ir4.x; ar[1]+=ir4.y; ar[2]+=ir4.z; ar[3]+=ir4.w; \
                        ai[0]+=ii4.x; ai[1]+=ii4.y; ai[2]+=ii4.z; ai[3]+=ii4.w; \
                    }                                                         \
                } else {                       /* b==4: -P1[ap] */            \
                    _Pragma("unroll") for (int j = 0; j < 4; ++j) {           \
                        ar[j] -= par_##s[j]; ai[j] -= pai_##s[j]; }           \
                }                                                             \
            } else {                                                          \
                if (qi < 4) {                  /* -conj(P1[b]) */             \
                    const float4 pr4 = LDSF4(SCOFF(8+qi,  up_##s) + c4);      \
                    const float4 pi4 = LDSF4(SCOFF(12+qi, up_##s) + c4);      \
                    ar[0]-=pr4.x; ar[1]-=pr4.y; ar[2]-=pr4.z; ar[3]-=pr4.w;   \
                    ai[0]+=pi4.x; ai[1]+=pi4.y; ai[2]+=pi4.z; ai[3]+=pi4.w;   \
                } else {                       /* 1/S1 */                     \
                    const float4 sr4 = LDSF4(SCOFF(24, up_##s) + c4);         \
                    const float4 si4 = LDSF4(SCOFF(25, up_##s) + c4);         \
                    ar[0]+=sr4.x; ar[1]+=sr4.y; ar[2]+=sr4.z; ar[3]+=sr4.w;   \
                    ai[0]+=si4.x; ai[1]+=si4.y; ai[2]+=si4.z; ai[3]+=si4.w;   \
                }                                                             \
            }                                                                 \
        }                                                                     \
    }                                                                         \
    ST4(out + (p##s*21+q)*N2 + j4,           ar[0], ar[1], ar[2], ar[3]);     \
    ST4(out + OUT_AIM + (p##s*21+q)*N2 + j4, ai[0], ai[1], ai[2], ai[3]);     \
    _Pragma("unroll") for (int j = 0; j < 4; ++j) {                           \
        zar_##s[j] += zq[j]*ar[j] - wq[j]*ai[j];                              \
        zai_##s[j] += zq[j]*ai[j] + wq[j]*ar[j]; }                            \
} while (0)

// tail q == 20 (h==0 lanes only)
#define SLOT_QTAIL(s) do {                                                    \
    float ar[4], ai[4];                                                       \
    _Pragma("unroll") for (int j = 0; j < 4; ++j) {                           \
        if (is20_##s) { ar[j] = is2r[j];       ai[j] = is2i[j]; }             \
        else          { ar[j] = -ppr_##s[j];   ai[j] = -ppi_##s[j]; } }       \
    ST4(out + (p##s*21+20)*N2 + j4,           ar[0], ar[1], ar[2], ar[3]);    \
    ST4(out + OUT_AIM + (p##s*21+20)*N2 + j4, ai[0], ai[1], ai[2], ai[3]);    \
    _Pragma("unroll") for (int j = 0; j < 4; ++j) {                           \
        zar_##s[j] += zq[j]*ar[j] - wq[j]*ai[j];                              \
        zai_##s[j] += zq[j]*ai[j] + wq[j]*ar[j]; }                            \
} while (0)

// reduce z across the 4 h-groups, redistribute to 1 col/lane, coalesced store
#define SLOT_ZFIN(s) do {                                                     \
    _Pragma("unroll") for (int j = 0; j < 4; ++j) {                           \
        zar_##s[j] += __shfl_xor(zar_##s[j], 16, 64);                         \
        zar_##s[j] += __shfl_xor(zar_##s[j], 32, 64);                         \
        zai_##s[j] += __shfl_xor(zai_##s[j], 16, 64);                         \
        zai_##s[j] += __shfl_xor(zai_##s[j], 32, 64); }                       \
    const int srcl = l >> 2;                                                  \
    const float ra = __shfl(zar_##s[0], srcl, 64);                            \
    const float rb = __shfl(zar_##s[1], srcl, 64);                            \
    const float rc = __shfl(zar_##s[2], srcl, 64);                            \
    const float rd = __shfl(zar_##s[3], srcl, 64);                            \
    const float ia = __shfl(zai_##s[0], srcl, 64);                            \
    const float ib = __shfl(zai_##s[1], srcl, 64);                            \
    const float ic = __shfl(zai_##s[2], srcl, 64);                            \
    const float id = __shfl(zai_##s[3], srcl, 64);                            \
    const int sel = l & 3;                                                    \
    const float zvr = sel==0 ? ra : sel==1 ? rb : sel==2 ? rc : rd;           \
    const float zvi = sel==0 ? ia : sel==1 ? ib : sel==2 ? ic : id;           \
    out[OUT_ZRE + p##s*N2 + j0 + l] = zvr;                                    \
    out[OUT_ZIM + p##s*N2 + j0 + l] = zvi;                                    \
} while (0)

// grid = (N2/64, 1), block = 896 threads (14 waves; 1 block/CU).
// R8 structure with DOUBLED wave count: wave g in 0..13 owns row p=g; waves
// g<7 additionally own p=g+14 (all 21 rows, max 2 rows/wave vs 3). More
// waves -> more outstanding stores per CU (R8 evidence: store-latency bound
// at 7 waves, 5 GB/s/CU, Occupancy 16.6%).
__global__ __launch_bounds__(896) void fused_kernel(
    const float* __restrict__ l00r, const float* __restrict__ l00i,
    const float* __restrict__ l01r, const float* __restrict__ l01i,
    const float* __restrict__ l02r, const float* __restrict__ l02i,
    const float* __restrict__ l11r, const float* __restrict__ l11i,
    const float* __restrict__ l12r, const float* __restrict__ l12i,
    const float* __restrict__ l22r, const float* __restrict__ l22i,
    const float* __restrict__ zre,  const float* __restrict__ zim,
    float* __restrict__ out, double* __restrict__ ld_partial)
{
    __shared__ float lds[L_TOT];
    const int t   = threadIdx.x;
    const int jl  = t & 63;
    const int j0  = blockIdx.x * 64;
    float ld = 0.f;

    // ================= phase 1: stage 0/1/2 per (u, jl) =================
    if (t < 256) {
        const int u = t >> 6;
        const int m = u * N2 + (j0 + jl);

        float i0r[4], i0i[4], t1r[4], t1i[4], p1r[4], p1i[4];
        float m1r = 0.f, m1i = 0.f;
#pragma unroll
        for (int k = 0; k < 4; ++k) {
            const int i = k * N1 + m;
            const float ar = l00r[i], ai = l00i[i];
            const float br = l01r[i], bi = l01i[i];
            const float d  = ar*ar + ai*ai;
            const float rd = 1.f / d;
            ld += 0.5f * logf(d);                   // log|lam00|
            const float xr = ar * rd, xi = -ai * rd;
            i0r[k] = xr; i0i[k] = xi;
            const float tr = br*xr - bi*xi;         // T1 = lam01/lam00
            const float ti = br*xi + bi*xr;
            t1r[k] = tr; t1i[k] = ti;
            m1r += br*tr + bi*ti;                   // conj(lam01)*T1
            m1i += br*ti - bi*tr;
        }
        const float s1r = l11r[m] - m1r;
        const float s1i = l11i[m] - m1i;
        const float ds1 = s1r*s1r + s1i*s1i;
        ld += 0.5f * logf(ds1);                     // log|S1|
        const float rds1 = 1.f / ds1;
        const float is1r = s1r * rds1, is1i = -s1i * rds1;
#pragma unroll
        for (int k = 0; k < 4; ++k) {
            p1r[k] = t1r[k]*is1r - t1i[k]*is1i;     // P1 = T1/S1
            p1i[k] = t1r[k]*is1i + t1i[k]*is1r;
        }

        // stage-2 B column: Bcol[a<4]=lam02[a*N1+m], Bcol[4]=lam12[m]
        float bcr[5], bci[5];
#pragma unroll
        for (int a = 0; a < 4; ++a) { bcr[a] = l02r[a*N1+m]; bci[a] = l02i[a*N1+m]; }
        bcr[4] = l12r[m]; bci[4] = l12i[m];

        // W = sum_{b<4} Bcol[b]*conj(T1[b]) - Bcol[4]
        float wr = -bcr[4], wi = -bci[4];
#pragma unroll
        for (int b = 0; b < 4; ++b) {
            wr += bcr[b]*t1r[b] + bci[b]*t1i[b];
            wi += bci[b]*t1r[b] - bcr[b]*t1i[b];
        }
        // T2 rows q = a*4+u
        float ur[5], ui[5];
#pragma unroll
        for (int a = 0; a < 4; ++a) {
            ur[a] = p1r[a]*wr - p1i[a]*wi + bcr[a]*i0r[a] - bci[a]*i0i[a];
            ui[a] = p1r[a]*wi + p1i[a]*wr + bcr[a]*i0i[a] + bci[a]*i0r[a];
        }
        {
            float vr = bcr[4]*is1r - bci[4]*is1i;   // Bcol[4]/S1
            float vi = bcr[4]*is1i + bci[4]*is1r;
#pragma unroll
            for (int b = 0; b < 4; ++b) {           // - Bcol[b]*conj(P1[b])
                vr -= bcr[b]*p1r[b] + bci[b]*p1i[b];
                vi -= bci[b]*p1r[b] - bcr[b]*p1i[b];
            }
            ur[4] = vr; ui[4] = vi;
        }
        float m2r = 0.f, m2i = 0.f;
#pragma unroll
        for (int a = 0; a < 5; ++a) {
            lds[L_T2R + (a*4+u)*T2STR + jl] = ur[a];
            lds[L_T2I + (a*4+u)*T2STR + jl] = ui[a];
            m2r += bcr[a]*ur[a] + bci[a]*ui[a];     // conj(B)*T2
            m2i += bcr[a]*ui[a] - bci[a]*ur[a];
        }
        lds[L_M2 + (0*4+u)*64 + jl] = m2r;
        lds[L_M2 + (1*4+u)*64 + jl] = m2i;
#pragma unroll
        for (int b = 0; b < 4; ++b) {
            SC(b,      u, jl) = t1r[b];  SC(4+b,  u, jl) = t1i[b];
            SC(8+b,    u, jl) = p1r[b];  SC(12+b, u, jl) = p1i[b];
            SC(16+b,   u, jl) = i0r[b];  SC(20+b, u, jl) = i0i[b];
        }
        SC(24, u, jl) = is1r;  SC(25, u, jl) = is1i;
    }
    __syncthreads();

    // ================= phase 1.5: S2 per column =================
    if (t < 64) {
        float s2r = l22r[j0 + t], s2i = l22i[j0 + t];
#pragma unroll
        for (int u = 0; u < 4; ++u) {
            s2r -= lds[L_M2 + (0*4+u)*64 + t];
            s2i -= lds[L_M2 + (1*4+u)*64 + t];
        }
        const float ds2  = s2r*s2r + s2i*s2i;
        const float rds2 = 1.f / ds2;
        lds[L_IS2R + t] =  s2r * rds2;
        lds[L_IS2I + t] = -s2i * rds2;
        ld += 0.5f * logf(ds2);                     // log|S2|
    }
    __syncthreads();

    // ===== phase 2: wave g -> rows {g} + {g+14 if g<7}; lane = (h, col quad) =====
    const int g  = t >> 6;                          // wave 0..13
    const int l  = t & 63;
    const int h  = l >> 4;                          // q ≡ h (mod 4)
    const int ci = l & 15;                          // column-quad index
    const int c4 = 4*ci;
    const int j4 = j0 + c4;                         // first of the 4 columns
    const bool live1 = (g < 7);                     // slot1 exists (wave-uniform)

    const float4 _r4 = LDSF4(L_IS2R + c4);
    const float4 _i4 = LDSF4(L_IS2I + c4);
    const float is2r[4] = {_r4.x, _r4.y, _r4.z, _r4.w};
    const float is2i[4] = {_i4.x, _i4.y, _i4.z, _i4.w};

    SLOT_PREP(0, g)
    SLOT_PREP(1, live1 ? g + 14 : g)                // clamp keeps LDS reads in-bounds

#pragma unroll
    for (int qi = 0; qi < 5; ++qi) {
        const int q = 4*qi + h;                     // < 20 always
        const float4 t4 = LDSF4(L_T2R + q*T2STR + c4);
        const float4 u4 = LDSF4(L_T2I + q*T2STR + c4);
        const float tq[4] = {t4.x, t4.y, t4.z, t4.w};
        const float uq[4] = {u4.x, u4.y, u4.z, u4.w};
        const float4 z4 = *reinterpret_cast<const float4*>(zre + q*N2 + j4);
        const float4 w4 = *reinterpret_cast<const float4*>(zim + q*N2 + j4);
        const float zq[4] = {z4.x, z4.y, z4.z, z4.w};
        const float wq[4] = {w4.x, w4.y, w4.z, w4.w};
        SLOT_QMAIN(0);
        if (live1) { SLOT_QMAIN(1); }
    }

    if (h == 0) {                                   // tail row q == 20
        const float4 z4 = *reinterpret_cast<const float4*>(zre + 20*N2 + j4);
        const float4 w4 = *reinterpret_cast<const float4*>(zim + 20*N2 + j4);
        const float zq[4] = {z4.x, z4.y, z4.z, z4.w};
        const float wq[4] = {w4.x, w4.y, w4.z, w4.w};
        SLOT_QTAIL(0);
        if (live1) { SLOT_QTAIL(1); }
    }

    SLOT_ZFIN(0);
    if (live1) { SLOT_ZFIN(1); }

    // ================= logdet block reduction -> ws partial =================
    {
        float v = ld;
#pragma unroll
        for (int off = 32; off > 0; off >>= 1) v += __shfl_down(v, off, 64);
        __syncthreads();                            // LDS reuse guard
        if (jl == 0) lds[L_RED + g] = v;
        __syncthreads();
        if (t == 0) {
            double s = 0.0;
#pragma unroll
            for (int w = 0; w < 14; ++w) s += (double)lds[L_RED + w];
            ld_partial[blockIdx.x] = s;
        }
    }
}

// 1 block, 256 threads: reduce the 256 double partials, write OUT_LD.
__global__ __launch_bounds__(256) void finalize_kernel(
    const double* __restrict__ part, float* __restrict__ out)
{
    double v = part[threadIdx.x];
#pragma unroll
    for (int off = 32; off > 0; off >>= 1) v += __shfl_down(v, off, 64);
    __shared__ double wsum[4];
    if ((threadIdx.x & 63) == 0) wsum[threadIdx.x >> 6] = v;
    __syncthreads();
    if (threadIdx.x == 0)
        out[OUT_LD] = (float)(wsum[0] + wsum[1] + wsum[2] + wsum[3]);
}

extern "C" void kernel_launch(void* const* d_in, const int* in_sizes, int n_in,
                              void* d_out, int out_size, void* d_ws, size_t ws_size,
                              hipStream_t stream)
{
    const float* l00r = (const float*)d_in[0];
    const float* l00i = (const float*)d_in[1];
    const float* l01r = (const float*)d_in[2];
    const float* l01i = (const float*)d_in[3];
    const float* l02r = (const float*)d_in[4];
    const float* l02i = (const float*)d_in[5];
    const float* l11r = (const float*)d_in[6];
    const float* l11i = (const float*)d_in[7];
    const float* l12r = (const float*)d_in[8];
    const float* l12i = (const float*)d_in[9];
    const float* l22r = (const float*)d_in[10];
    const float* l22i = (const float*)d_in[11];
    const float* zre  = (const float*)d_in[12];
    const float* zim  = (const float*)d_in[13];
    float*  out        = (float*)d_out;
    double* ld_partial = (double*)d_ws;             // 256 doubles, rewritten each call

    fused_kernel<<<dim3(N2/64, 1), dim3(896), 0, stream>>>(
        l00r,l00i,l01r,l01i,l02r,l02i,l11r,l11i,l12r,l12i,l22r,l22i,
        zre,zim, out, ld_partial);
    finalize_kernel<<<1, 256, 0, stream>>>(ld_partial, out);
}

// Round 10
// 121.822 us; speedup vs baseline: 1.0752x; 1.0752x over previous
//
#include <hip/hip_runtime.h>

#define N2 16384
#define N1 65536

// ---- output layout (float offsets) ----
#define OUT_AIM 7225344         // 21*21*N2
#define OUT_LD  14450688        // 2*21*21*N2
#define OUT_ZRE 14450689
#define OUT_ZIM 14794753        // OUT_ZRE + 21*N2

// ---- workspace layout (float offsets into d_ws; re-poisoned each iteration,
//      but every word read below is written by schur_kernel first) ----
#define WS_T2R  0               // [20][N2]
#define WS_T2I  (20*N2)         // [20][N2]
#define WS_IS2R (40*N2)         // [N2]
#define WS_IS2I (41*N2)         // [N2]
#define WS_SC   (42*N2)         // [26][4][N2]
//   idx 0..3 t1r[b], 4..7 t1i[b], 8..11 p1r[b], 12..15 p1i[b],
//   idx 16..19 i0r[a], 20..23 i0i[a], 24 is1r, 25 is1i
#define WS_FLOATS (146*N2)      // 9.57 MB; ld_partial (256 doubles) follows

// =====================================================================
// K1: per-column Schur chain -> ws intermediates + logdet partials.
// grid (N2/64) x 256 threads (u = t>>6, jl = t&63). Identical math to the
// previous fused phase 1 / 1.5; LDS only for the cross-u M2 reduce.
// =====================================================================
__global__ __launch_bounds__(256) void schur_kernel(
    const float* __restrict__ l00r, const float* __restrict__ l00i,
    const float* __restrict__ l01r, const float* __restrict__ l01i,
    const float* __restrict__ l02r, const float* __restrict__ l02i,
    const float* __restrict__ l11r, const float* __restrict__ l11i,
    const float* __restrict__ l12r, const float* __restrict__ l12i,
    const float* __restrict__ l22r, const float* __restrict__ l22i,
    float* __restrict__ ws, double* __restrict__ ld_partial)
{
    __shared__ float lds[520];                      // M2 [2][4][64] + RED[4]
    const int t  = threadIdx.x;
    const int u  = t >> 6;
    const int jl = t & 63;
    const int j0 = blockIdx.x * 64;
    const int j  = j0 + jl;
    const int m  = u * N2 + j;
    float ld = 0.f;

#define SCW(idx) ws[WS_SC + ((idx)*4 + u)*N2 + j]

    {
        float i0r[4], i0i[4], t1r[4], t1i[4], p1r[4], p1i[4];
        float m1r = 0.f, m1i = 0.f;
#pragma unroll
        for (int k = 0; k < 4; ++k) {
            const int i = k * N1 + m;
            const float ar = l00r[i], ai = l00i[i];
            const float br = l01r[i], bi = l01i[i];
            const float d  = ar*ar + ai*ai;
            const float rd = 1.f / d;
            ld += 0.5f * logf(d);                   // log|lam00|
            const float xr = ar * rd, xi = -ai * rd;
            i0r[k] = xr; i0i[k] = xi;
            const float tr = br*xr - bi*xi;         // T1 = lam01/lam00
            const float ti = br*xi + bi*xr;
            t1r[k] = tr; t1i[k] = ti;
            m1r += br*tr + bi*ti;                   // conj(lam01)*T1
            m1i += br*ti - bi*tr;
        }
        const float s1r = l11r[m] - m1r;
        const float s1i = l11i[m] - m1i;
        const float ds1 = s1r*s1r + s1i*s1i;
        ld += 0.5f * logf(ds1);                     // log|S1|
        const float rds1 = 1.f / ds1;
        const float is1r = s1r * rds1, is1i = -s1i * rds1;
#pragma unroll
        for (int k = 0; k < 4; ++k) {
            p1r[k] = t1r[k]*is1r - t1i[k]*is1i;     // P1 = T1/S1
            p1i[k] = t1r[k]*is1i + t1i[k]*is1r;
        }

        float bcr[5], bci[5];
#pragma unroll
        for (int a = 0; a < 4; ++a) { bcr[a] = l02r[a*N1+m]; bci[a] = l02i[a*N1+m]; }
        bcr[4] = l12r[m]; bci[4] = l12i[m];

        float wr = -bcr[4], wi = -bci[4];           // W = sum B*conj(T1) - B[4]
#pragma unroll
        for (int b = 0; b < 4; ++b) {
            wr += bcr[b]*t1r[b] + bci[b]*t1i[b];
            wi += bci[b]*t1r[b] - bcr[b]*t1i[b];
        }
        float ur[5], ui[5];                         // T2 rows q = a*4+u
#pragma unroll
        for (int a = 0; a < 4; ++a) {
            ur[a] = p1r[a]*wr - p1i[a]*wi + bcr[a]*i0r[a] - bci[a]*i0i[a];
            ui[a] = p1r[a]*wi + p1i[a]*wr + bcr[a]*i0i[a] + bci[a]*i0r[a];
        }
        {
            float vr = bcr[4]*is1r - bci[4]*is1i;   // Bcol[4]/S1
            float vi = bcr[4]*is1i + bci[4]*is1r;
#pragma unroll
            for (int b = 0; b < 4; ++b) {           // - Bcol[b]*conj(P1[b])
                vr -= bcr[b]*p1r[b] + bci[b]*p1i[b];
                vi -= bci[b]*p1r[b] - bcr[b]*p1i[b];
            }
            ur[4] = vr; ui[4] = vi;
        }
        float m2r = 0.f, m2i = 0.f;
#pragma unroll
        for (int a = 0; a < 5; ++a) {
            ws[WS_T2R + (a*4+u)*N2 + j] = ur[a];
            ws[WS_T2I + (a*4+u)*N2 + j] = ui[a];
            m2r += bcr[a]*ur[a] + bci[a]*ui[a];     // conj(B)*T2
            m2i += bcr[a]*ui[a] - bci[a]*ur[a];
        }
        lds[(0*4+u)*64 + jl] = m2r;
        lds[(1*4+u)*64 + jl] = m2i;
#pragma unroll
        for (int b = 0; b < 4; ++b) {
            SCW(b)      = t1r[b];  SCW(4+b)  = t1i[b];
            SCW(8+b)    = p1r[b];  SCW(12+b) = p1i[b];
            SCW(16+b)   = i0r[b];  SCW(20+b) = i0i[b];
        }
        SCW(24) = is1r;  SCW(25) = is1i;
    }
    __syncthreads();

    if (t < 64) {                                   // S2 per column
        float s2r = l22r[j0 + t], s2i = l22i[j0 + t];
#pragma unroll
        for (int uu = 0; uu < 4; ++uu) {
            s2r -= lds[(0*4+uu)*64 + t];
            s2i -= lds[(1*4+uu)*64 + t];
        }
        const float ds2  = s2r*s2r + s2i*s2i;
        const float rds2 = 1.f / ds2;
        ws[WS_IS2R + j0 + t] =  s2r * rds2;
        ws[WS_IS2I + j0 + t] = -s2i * rds2;
        ld += 0.5f * logf(ds2);                     // log|S2|
    }

    {                                               // logdet partial -> ws
        float v = ld;
#pragma unroll
        for (int off = 32; off > 0; off >>= 1) v += __shfl_down(v, off, 64);
        __syncthreads();
        if (jl == 0) lds[512 + (t >> 6)] = v;
        __syncthreads();
        if (t == 0) {
            double s = 0.0;
#pragma unroll
            for (int w = 0; w < 4; ++w) s += (double)lds[512 + w];
            ld_partial[blockIdx.x] = s;
        }
    }
#undef SCW
}

// =====================================================================
// K2: writer. grid (32, 21): blockIdx.x = 512-col span, blockIdx.y = p.
// Each block writes 21 output rows x 2 KB contiguous chunks whose channel
// index varies with both cs and q -> no per-block channel camping (the R9
// diagnosis: 64-col tiles put a block's whole 236 KB on one channel).
// Thread owns 2 adjacent cols; z-accumulation is thread-local.
// =====================================================================
__global__ __launch_bounds__(256) void write_kernel(
    const float* __restrict__ zre, const float* __restrict__ zim,
    const float* __restrict__ ws, const double* __restrict__ ld_partial,
    float* __restrict__ out)
{
    const int p = blockIdx.y;                       // 0..20
    const int j = blockIdx.x * 512 + threadIdx.x * 2;

#define WF2(off)      (*reinterpret_cast<const float2*>(ws + (off) + j))
#define SCF2(idx,uu)  (*reinterpret_cast<const float2*>(ws + WS_SC + ((idx)*4 + (uu))*N2 + j))
#define OST2(off, a, b) do { float2 _o; _o.x=(a); _o.y=(b);                   \
    *reinterpret_cast<float2*>(out + (off) + j) = _o; } while (0)

    const float2 i2r = WF2(WS_IS2R);
    const float2 i2i = WF2(WS_IS2I);

    const bool is20 = (p == 20);
    const int  ap = p >> 2, up = p & 3;
    float pr0=0.f, pi0=0.f, pr1=0.f, pi1=0.f;       // P2[p] (2 cols)
    float2 par = {0.f, 0.f}, pai = {0.f, 0.f};      // P1[ap] at u=up
    if (!is20) {
        const float2 t2r = WF2(WS_T2R + p*N2);
        const float2 t2i = WF2(WS_T2I + p*N2);
        pr0 = t2r.x*i2r.x - t2i.x*i2i.x;  pi0 = t2r.x*i2i.x + t2i.x*i2r.x;
        pr1 = t2r.y*i2r.y - t2i.y*i2i.y;  pi1 = t2r.y*i2i.y + t2i.y*i2r.y;
        if (ap < 4) { par = SCF2(8+ap, up);  pai = SCF2(12+ap, up); }
    }

    float zar0=0.f, zai0=0.f, zar1=0.f, zai1=0.f;

#pragma unroll
    for (int q = 0; q < 20; ++q) {
        const float2 tq = WF2(WS_T2R + q*N2);
        const float2 uq = WF2(WS_T2I + q*N2);
        const float2 zr = *reinterpret_cast<const float2*>(zre + q*N2 + j);
        const float2 zi = *reinterpret_cast<const float2*>(zim + q*N2 + j);
        float ar0, ai0, ar1, ai1;
        if (is20) {                                 // row 20: -conj(P2[q])
            ar0 = -(tq.x*i2r.x - uq.x*i2i.x);  ai0 = tq.x*i2i.x + uq.x*i2r.x;
            ar1 = -(tq.y*i2r.y - uq.y*i2i.y);  ai1 = tq.y*i2i.y + uq.y*i2r.y;
        } else {                                    // P2[p]*conj(T2[q])
            ar0 = pr0*tq.x + pi0*uq.x;  ai0 = pi0*tq.x - pr0*uq.x;
            ar1 = pr1*tq.y + pi1*uq.y;  ai1 = pi1*tq.y - pr1*uq.y;
            if ((q & 3) == up) {                    // + A1[ap][q>>2] scatter
                const int b = q >> 2;               // compile-time (unrolled)
                if (ap < 4) {
                    if (b < 4) {
                        const float2 tb = SCF2(b,   up);
                        const float2 ub = SCF2(4+b, up);
                        ar0 += par.x*tb.x + pai.x*ub.x;  ai0 += pai.x*tb.x - par.x*ub.x;
                        ar1 += par.y*tb.y + pai.y*ub.y;  ai1 += pai.y*tb.y - par.y*ub.y;
                        if (b == ap) {              // + 1/lam00
                            const float2 dr = SCF2(16+ap, up);
                            const float2 di = SCF2(20+ap, up);
                            ar0 += dr.x; ai0 += di.x; ar1 += dr.y; ai1 += di.y;
                        }
                    } else {                        // b==4: -P1[ap]
                        ar0 -= par.x; ai0 -= pai.x; ar1 -= par.y; ai1 -= pai.y;
                    }
                } else {
                    if (b < 4) {                    // -conj(P1[b])
                        const float2 qr = SCF2(8+b,  up);
                        const float2 qi = SCF2(12+b, up);
                        ar0 -= qr.x; ai0 += qi.x; ar1 -= qr.y; ai1 += qi.y;
                    } else {                        // 1/S1
                        const float2 sr = SCF2(24, up);
                        const float2 si = SCF2(25, up);
                        ar0 += sr.x; ai0 += si.x; ar1 += sr.y; ai1 += si.y;
                    }
                }
            }
        }
        OST2((p*21+q)*N2,           ar0, ar1);
        OST2(OUT_AIM + (p*21+q)*N2, ai0, ai1);
        zar0 += zr.x*ar0 - zi.x*ai0;  zai0 += zr.x*ai0 + zi.x*ar0;
        zar1 += zr.y*ar1 - zi.y*ai1;  zai1 += zr.y*ai1 + zi.y*ar1;
    }
    {                                               // q == 20
        const float2 zr = *reinterpret_cast<const float2*>(zre + 20*N2 + j);
        const float2 zi = *reinterpret_cast<const float2*>(zim + 20*N2 + j);
        float ar0, ai0, ar1, ai1;
        if (is20) { ar0 = i2r.x; ai0 = i2i.x; ar1 = i2r.y; ai1 = i2i.y; }
        else      { ar0 = -pr0;  ai0 = -pi0;  ar1 = -pr1;  ai1 = -pi1; }
        OST2((p*21+20)*N2,           ar0, ar1);
        OST2(OUT_AIM + (p*21+20)*N2, ai0, ai1);
        zar0 += zr.x*ar0 - zi.x*ai0;  zai0 += zr.x*ai0 + zi.x*ar0;
        zar1 += zr.y*ar1 - zi.y*ai1;  zai1 += zr.y*ai1 + zi.y*ar1;
    }

    // zout (OUT_ZRE base is odd -> 4B-aligned scalar stores)
    out[OUT_ZRE + p*N2 + j]     = zar0;
    out[OUT_ZRE + p*N2 + j + 1] = zar1;
    out[OUT_ZIM + p*N2 + j]     = zai0;
    out[OUT_ZIM + p*N2 + j + 1] = zai1;

    // logdet finalize folded into block (0,0) — depends only on K1 results
    if (blockIdx.x == 0 && p == 0) {
        __shared__ double wsum[4];
        double v = ld_partial[threadIdx.x];         // 256 partials
#pragma unroll
        for (int off = 32; off > 0; off >>= 1) v += __shfl_down(v, off, 64);
        if ((threadIdx.x & 63) == 0) wsum[threadIdx.x >> 6] = v;
        __syncthreads();
        if (threadIdx.x == 0)
            out[OUT_LD] = (float)(wsum[0] + wsum[1] + wsum[2] + wsum[3]);
    }
#undef WF2
#undef SCF2
#undef OST2
}

extern "C" void kernel_launch(void* const* d_in, const int* in_sizes, int n_in,
                              void* d_out, int out_size, void* d_ws, size_t ws_size,
                              hipStream_t stream)
{
    const float* l00r = (const float*)d_in[0];
    const float* l00i = (const float*)d_in[1];
    const float* l01r = (const float*)d_in[2];
    const float* l01i = (const float*)d_in[3];
    const float* l02r = (const float*)d_in[4];
    const float* l02i = (const float*)d_in[5];
    const float* l11r = (const float*)d_in[6];
    const float* l11i = (const float*)d_in[7];
    const float* l12r = (const float*)d_in[8];
    const float* l12i = (const float*)d_in[9];
    const float* l22r = (const float*)d_in[10];
    const float* l22i = (const float*)d_in[11];
    const float* zre  = (const float*)d_in[12];
    const float* zim  = (const float*)d_in[13];
    float*  out = (float*)d_out;
    float*  wsf = (float*)d_ws;
    double* ldp = (double*)(wsf + WS_FLOATS);       // 8B-aligned (146*N2*4 bytes)

    schur_kernel<<<dim3(N2/64), dim3(256), 0, stream>>>(
        l00r,l00i,l01r,l01i,l02r,l02i,l11r,l11i,l12r,l12i,l22r,l22i,
        wsf, ldp);
    write_kernel<<<dim3(32, 21), dim3(256), 0, stream>>>(
        zre, zim, wsf, ldp, out);
}

// Round 11
// 111.685 us; speedup vs baseline: 1.1728x; 1.0908x over previous
//
#include <hip/hip_runtime.h>

#define N2 16384
#define N1 65536

// ---- output layout (float offsets) ----
#define OUT_AIM 7225344         // 21*21*N2
#define OUT_LD  14450688        // 2*21*21*N2
#define OUT_ZRE 14450689
#define OUT_ZIM 14794753        // OUT_ZRE + 21*N2

// ---- LDS layout (float offsets), TILE_J = 64 ----
#define L_T2R  0                // [20][64]
#define L_T2I  1280
#define L_M2   2560             // [c:2][u:4][64]
#define L_SC   3072             // [idx:26][u:4][64]
#define L_IS2R 9728             // [64]
#define L_IS2I 9792
#define L_RED  9856             // [7]
#define L_ZR   9872             // [21][64]  z_re tile (16B-aligned)
#define L_ZI   11216            // [21][64]  z_im tile
#define L_TOT  12560            // ~50.2 KB

#define SC(idx, u, jl) lds[L_SC + (((idx)*4 + (u)) * 64) + (jl)]

// ---- workspace: 256 doubles (per-block logdet partials), reduced by the
// tiny finalize dispatch (stream-ordered; kernel-boundary release/acquire).

// packed 8-byte plain store of two adjacent floats
#define ST2(addr, v0, v1) do {                                     \
    union { float f[2]; long L; } _u; _u.f[0] = (v0); _u.f[1] = (v1); \
    *(long*)(addr) = _u.L; } while (0)

// ---- phase-2 per-row-slot machinery (3 rows per wave-group) ----
// KEY CHANGE vs R7: phase 2 reads z from LDS (preloaded by waves 4-6 during
// phase 1), so the q-loop contains NO global loads. vmcnt counts loads AND
// stores in order; a z-load wait inside the loop was draining the store
// queue to memory-ack every iteration (the ~44us invariant across NT/width/
// occupancy/layout variants). Now the store stream runs wait-free.
#define SLOT_PREP(s, P)                                                       \
    const int  p##s    = (P);                                                 \
    const bool is20_##s = (p##s == 20);                                       \
    const int  ap_##s  = p##s >> 2, up_##s = p##s & 3;                        \
    float ppr0_##s=0.f, ppi0_##s=0.f, ppr1_##s=0.f, ppi1_##s=0.f;             \
    float par0_##s=0.f, pai0_##s=0.f, par1_##s=0.f, pai1_##s=0.f;             \
    if (!is20_##s) {                                                          \
        const float tpr0 = lds[L_T2R + p##s*64 + c2], tpr1 = lds[L_T2R + p##s*64 + c2+1]; \
        const float tpi0 = lds[L_T2I + p##s*64 + c2], tpi1 = lds[L_T2I + p##s*64 + c2+1]; \
        ppr0_##s = tpr0*is2r0 - tpi0*is2i0;  ppi0_##s = tpr0*is2i0 + tpi0*is2r0; \
        ppr1_##s = tpr1*is2r1 - tpi1*is2i1;  ppi1_##s = tpr1*is2i1 + tpi1*is2r1; \
        if (ap_##s < 4) {                                                     \
            par0_##s = SC(8+ap_##s,  up_##s, c2);   pai0_##s = SC(12+ap_##s, up_##s, c2);   \
            par1_##s = SC(8+ap_##s,  up_##s, c2+1); pai1_##s = SC(12+ap_##s, up_##s, c2+1); \
        }                                                                     \
    }                                                                         \
    float zar0_##s=0.f, zai0_##s=0.f, zar1_##s=0.f, zai1_##s=0.f;

#define SLOT_Q(s) do {                                                        \
    float ar0, ai0, ar1, ai1;                                                 \
    if (is20_##s) {                                                           \
        if (q < 20) {                                                         \
            ar0 = -(tr0*is2r0 - ti0*is2i0);  ai0 = tr0*is2i0 + ti0*is2r0;     \
            ar1 = -(tr1*is2r1 - ti1*is2i1);  ai1 = tr1*is2i1 + ti1*is2r1;     \
        } else { ar0=is2r0; ai0=is2i0; ar1=is2r1; ai1=is2i1; }                \
    } else if (q < 20) {                                                      \
        ar0 = ppr0_##s*tr0 + ppi0_##s*ti0;  ai0 = ppi0_##s*tr0 - ppr0_##s*ti0;\
        ar1 = ppr1_##s*tr1 + ppi1_##s*ti1;  ai1 = ppi1_##s*tr1 - ppr1_##s*ti1;\
        if ((q & 3) == up_##s) {            /* + A1[ap][q>>2] scatter */      \
            const int b = q >> 2;                                             \
            if (ap_##s < 4) {                                                 \
                if (b < 4) {                                                  \
                    const float tbr0 = SC(b, up_##s, c2),   tbi0 = SC(4+b, up_##s, c2);   \
                    const float tbr1 = SC(b, up_##s, c2+1), tbi1 = SC(4+b, up_##s, c2+1); \
                    ar0 += par0_##s*tbr0 + pai0_##s*tbi0;  ai0 += pai0_##s*tbr0 - par0_##s*tbi0; \
                    ar1 += par1_##s*tbr1 + pai1_##s*tbi1;  ai1 += pai1_##s*tbr1 - par1_##s*tbi1; \
                    if (b == ap_##s) {             /* + 1/lam00 */            \
                        ar0 += SC(16+ap_##s, up_##s, c2);   ai0 += SC(20+ap_##s, up_##s, c2);   \
                        ar1 += SC(16+ap_##s, up_##s, c2+1); ai1 += SC(20+ap_##s, up_##s, c2+1); \
                    }                                                         \
                } else { ar0 -= par0_##s; ai0 -= pai0_##s; ar1 -= par1_##s; ai1 -= pai1_##s; } \
            } else {                                                          \
                if (b < 4) {                       /* -conj(P1[b]) */         \
                    ar0 -= SC(8+b, up_##s, c2);   ai0 += SC(12+b, up_##s, c2);   \
                    ar1 -= SC(8+b, up_##s, c2+1); ai1 += SC(12+b, up_##s, c2+1); \
                } else {                           /* 1/S1 */                 \
                    ar0 += SC(24, up_##s, c2);   ai0 += SC(25, up_##s, c2);   \
                    ar1 += SC(24, up_##s, c2+1); ai1 += SC(25, up_##s, c2+1); \
                }                                                             \
            }                                                                 \
        }                                                                     \
    } else { ar0 = -ppr0_##s; ai0 = -ppi0_##s; ar1 = -ppr1_##s; ai1 = -ppi1_##s; } \
    ST2(out + (p##s*21+q)*N2 + j2,           ar0, ar1);                       \
    ST2(out + OUT_AIM + (p##s*21+q)*N2 + j2, ai0, ai1);                       \
    zar0_##s += zr2.x*ar0 - zi2.x*ai0;  zai0_##s += zr2.x*ai0 + zi2.x*ar0;    \
    zar1_##s += zr2.y*ar1 - zi2.y*ai1;  zai1_##s += zr2.y*ai1 + zi2.y*ar1;    \
} while (0)

#define SLOT_ZSTORE(s) do {                                                   \
    float a0 = zar0_##s, b0 = zai0_##s, a1 = zar1_##s, b1 = zai1_##s;         \
    a0 += __shfl_xor(a0, 32, 64);  b0 += __shfl_xor(b0, 32, 64);              \
    a1 += __shfl_xor(a1, 32, 64);  b1 += __shfl_xor(b1, 32, 64);              \
    const int src = l >> 1;                                                   \
    const float e_r = __shfl(a0, src, 64), o_r = __shfl(a1, src, 64);         \
    const float e_i = __shfl(b0, src, 64), o_i = __shfl(b1, src, 64);         \
    const float zvr = (l & 1) ? o_r : e_r;                                    \
    const float zvi = (l & 1) ? o_i : e_i;                                    \
    out[OUT_ZRE + p##s*N2 + j0 + l] = zvr;                                    \
    out[OUT_ZIM + p##s*N2 + j0 + l] = zvi;                                    \
} while (0)

// grid = (N2/64, 1), block = 448 threads (7 waves).
// Phase 1: waves 0-3 run the Schur chain; waves 4-6 preload the z tile into
// LDS (their global-load vmcnt waits overlap phase-1 compute). Phase 2:
// wave-group g emits rows p = g, g+7, g+14 with a global-load-free q-loop.
__global__ __launch_bounds__(448) void fused_kernel(
    const float* __restrict__ l00r, const float* __restrict__ l00i,
    const float* __restrict__ l01r, const float* __restrict__ l01i,
    const float* __restrict__ l02r, const float* __restrict__ l02i,
    const float* __restrict__ l11r, const float* __restrict__ l11i,
    const float* __restrict__ l12r, const float* __restrict__ l12i,
    const float* __restrict__ l22r, const float* __restrict__ l22i,
    const float* __restrict__ zre,  const float* __restrict__ zim,
    float* __restrict__ out, double* __restrict__ ld_partial)
{
    __shared__ float lds[L_TOT];
    const int t   = threadIdx.x;
    const int jl  = t & 63;
    const int j0  = blockIdx.x * 64;
    float ld = 0.f;

    // ================= phase 1: stage 0/1/2 per (u, jl) =================
    if (t < 256) {
        const int u = t >> 6;
        const int m = u * N2 + (j0 + jl);

        float i0r[4], i0i[4], t1r[4], t1i[4], p1r[4], p1i[4];
        float m1r = 0.f, m1i = 0.f;
#pragma unroll
        for (int k = 0; k < 4; ++k) {
            const int i = k * N1 + m;
            const float ar = l00r[i], ai = l00i[i];
            const float br = l01r[i], bi = l01i[i];
            const float d  = ar*ar + ai*ai;
            const float rd = 1.f / d;
            ld += 0.5f * logf(d);                   // log|lam00|
            const float xr = ar * rd, xi = -ai * rd;
            i0r[k] = xr; i0i[k] = xi;
            const float tr = br*xr - bi*xi;         // T1 = lam01/lam00
            const float ti = br*xi + bi*xr;
            t1r[k] = tr; t1i[k] = ti;
            m1r += br*tr + bi*ti;                   // conj(lam01)*T1
            m1i += br*ti - bi*tr;
        }
        const float s1r = l11r[m] - m1r;
        const float s1i = l11i[m] - m1i;
        const float ds1 = s1r*s1r + s1i*s1i;
        ld += 0.5f * logf(ds1);                     // log|S1|
        const float rds1 = 1.f / ds1;
        const float is1r = s1r * rds1, is1i = -s1i * rds1;
#pragma unroll
        for (int k = 0; k < 4; ++k) {
            p1r[k] = t1r[k]*is1r - t1i[k]*is1i;     // P1 = T1/S1
            p1i[k] = t1r[k]*is1i + t1i[k]*is1r;
        }

        // stage-2 B column: Bcol[a<4]=lam02[a*N1+m], Bcol[4]=lam12[m]
        float bcr[5], bci[5];
#pragma unroll
        for (int a = 0; a < 4; ++a) { bcr[a] = l02r[a*N1+m]; bci[a] = l02i[a*N1+m]; }
        bcr[4] = l12r[m]; bci[4] = l12i[m];

        // W = sum_{b<4} Bcol[b]*conj(T1[b]) - Bcol[4]
        float wr = -bcr[4], wi = -bci[4];
#pragma unroll
        for (int b = 0; b < 4; ++b) {
            wr += bcr[b]*t1r[b] + bci[b]*t1i[b];
            wi += bci[b]*t1r[b] - bcr[b]*t1i[b];
        }
        // T2 rows q = a*4+u
        float ur[5], ui[5];
#pragma unroll
        for (int a = 0; a < 4; ++a) {
            ur[a] = p1r[a]*wr - p1i[a]*wi + bcr[a]*i0r[a] - bci[a]*i0i[a];
            ui[a] = p1r[a]*wi + p1i[a]*wr + bcr[a]*i0i[a] + bci[a]*i0r[a];
        }
        {
            float vr = bcr[4]*is1r - bci[4]*is1i;   // Bcol[4]/S1
            float vi = bcr[4]*is1i + bci[4]*is1r;
#pragma unroll
            for (int b = 0; b < 4; ++b) {           // - Bcol[b]*conj(P1[b])
                vr -= bcr[b]*p1r[b] + bci[b]*p1i[b];
                vi -= bci[b]*p1r[b] - bcr[b]*p1i[b];
            }
            ur[4] = vr; ui[4] = vi;
        }
        float m2r = 0.f, m2i = 0.f;
#pragma unroll
        for (int a = 0; a < 5; ++a) {
            lds[L_T2R + (a*4+u)*64 + jl] = ur[a];
            lds[L_T2I + (a*4+u)*64 + jl] = ui[a];
            m2r += bcr[a]*ur[a] + bci[a]*ui[a];     // conj(B)*T2
            m2i += bcr[a]*ui[a] - bci[a]*ur[a];
        }
        lds[L_M2 + (0*4+u)*64 + jl] = m2r;
        lds[L_M2 + (1*4+u)*64 + jl] = m2i;
#pragma unroll
        for (int b = 0; b < 4; ++b) {
            SC(b,      u, jl) = t1r[b];  SC(4+b,  u, jl) = t1i[b];
            SC(8+b,    u, jl) = p1r[b];  SC(12+b, u, jl) = p1i[b];
            SC(16+b,   u, jl) = i0r[b];  SC(20+b, u, jl) = i0i[b];
        }
        SC(24, u, jl) = is1r;  SC(25, u, jl) = is1i;
    } else {
        // ===== waves 4-6: preload z tile into LDS (overlaps phase 1) =====
        const int idx = t - 256;                    // 0..191
        for (int cc = idx; cc < 672; cc += 192) {   // 672 float4 chunks
            const bool im = cc >= 336;
            const int c  = im ? cc - 336 : cc;
            const int q  = c >> 4;                  // row 0..20
            const int c4 = (c & 15) << 2;           // col 0..60 step 4
            const float4 v = *reinterpret_cast<const float4*>(
                (im ? zim : zre) + q*N2 + j0 + c4);
            *reinterpret_cast<float4*>(&lds[(im ? L_ZI : L_ZR) + q*64 + c4]) = v;
        }
    }
    __syncthreads();

    // ================= phase 1.5: S2 per column =================
    if (t < 64) {
        float s2r = l22r[j0 + t], s2i = l22i[j0 + t];
#pragma unroll
        for (int u = 0; u < 4; ++u) {
            s2r -= lds[L_M2 + (0*4+u)*64 + t];
            s2i -= lds[L_M2 + (1*4+u)*64 + t];
        }
        const float ds2  = s2r*s2r + s2i*s2i;
        const float rds2 = 1.f / ds2;
        lds[L_IS2R + t] =  s2r * rds2;
        lds[L_IS2I + t] = -s2i * rds2;
        ld += 0.5f * logf(ds2);                     // log|S2|
    }
    __syncthreads();

    // ===== phase 2: rows p = g, g+7, g+14; lane = (h: q-parity, c: col pair) =====
    const int g  = t >> 6;                          // wave group 0..6
    const int l  = t & 63;
    const int h  = l >> 5;                          // q parity
    const int c  = l & 31;                          // column-pair index
    const int c2 = 2*c;
    const int j2 = j0 + c2;                         // first of the 2 columns

    const float is2r0 = lds[L_IS2R + c2],   is2r1 = lds[L_IS2R + c2+1];
    const float is2i0 = lds[L_IS2I + c2],   is2i1 = lds[L_IS2I + c2+1];

    SLOT_PREP(0, g)
    SLOT_PREP(1, g + 7)
    SLOT_PREP(2, g + 14)

#pragma unroll
    for (int qi = 0; qi < 11; ++qi) {
        const int q = 2*qi + h;
        if (q >= 21) continue;
        float tr0=0.f, tr1=0.f, ti0=0.f, ti1=0.f;
        if (q < 20) {
            tr0 = lds[L_T2R + q*64 + c2];  tr1 = lds[L_T2R + q*64 + c2+1];
            ti0 = lds[L_T2I + q*64 + c2];  ti1 = lds[L_T2I + q*64 + c2+1];
        }
        const float2 zr2 = *reinterpret_cast<const float2*>(&lds[L_ZR + q*64 + c2]);
        const float2 zi2 = *reinterpret_cast<const float2*>(&lds[L_ZI + q*64 + c2]);
        SLOT_Q(0);
        SLOT_Q(1);
        SLOT_Q(2);
    }

    SLOT_ZSTORE(0);
    SLOT_ZSTORE(1);
    SLOT_ZSTORE(2);

    // ================= logdet block reduction -> ws partial =================
    {
        float v = ld;
#pragma unroll
        for (int off = 32; off > 0; off >>= 1) v += __shfl_down(v, off, 64);
        __syncthreads();                            // LDS reuse guard
        if (jl == 0) lds[L_RED + g] = v;
        __syncthreads();
        if (t == 0) {
            double s = 0.0;
#pragma unroll
            for (int w = 0; w < 7; ++w) s += (double)lds[L_RED + w];
            ld_partial[blockIdx.x] = s;
        }
    }
}

// 1 block, 256 threads: reduce the 256 double partials, write OUT_LD.
__global__ __launch_bounds__(256) void finalize_kernel(
    const double* __restrict__ part, float* __restrict__ out)
{
    double v = part[threadIdx.x];
#pragma unroll
    for (int off = 32; off > 0; off >>= 1) v += __shfl_down(v, off, 64);
    __shared__ double wsum[4];
    if ((threadIdx.x & 63) == 0) wsum[threadIdx.x >> 6] = v;
    __syncthreads();
    if (threadIdx.x == 0)
        out[OUT_LD] = (float)(wsum[0] + wsum[1] + wsum[2] + wsum[3]);
}

extern "C" void kernel_launch(void* const* d_in, const int* in_sizes, int n_in,
                              void* d_out, int out_size, void* d_ws, size_t ws_size,
                              hipStream_t stream)
{
    const float* l00r = (const float*)d_in[0];
    const float* l00i = (const float*)d_in[1];
    const float* l01r = (const float*)d_in[2];
    const float* l01i = (const float*)d_in[3];
    const float* l02r = (const float*)d_in[4];
    const float* l02i = (const float*)d_in[5];
    const float* l11r = (const float*)d_in[6];
    const float* l11i = (const float*)d_in[7];
    const float* l12r = (const float*)d_in[8];
    const float* l12i = (const float*)d_in[9];
    const float* l22r = (const float*)d_in[10];
    const float* l22i = (const float*)d_in[11];
    const float* zre  = (const float*)d_in[12];
    const float* zim  = (const float*)d_in[13];
    float*  out        = (float*)d_out;
    double* ld_partial = (double*)d_ws;             // 256 doubles, rewritten each call

    fused_kernel<<<dim3(N2/64, 1), dim3(448), 0, stream>>>(
        l00r,l00i,l01r,l01i,l02r,l02i,l11r,l11i,l12r,l12i,l22r,l22i,
        zre,zim, out, ld_partial);
    finalize_kernel<<<1, 256, 0, stream>>>(ld_partial, out);
}